// Round 6
// baseline (219.754 us; speedup 1.0000x reference)
//
#include <hip/hip_runtime.h>
#include <hip/hip_bf16.h>

// Problem constants (fixed by reference): N=4096, D=256, T=0.5, EPS=1e-8
#define PN   4096
#define PN2  8192
#define PD   256
#define TILE 128
#define NBLK (PN2 / TILE)             // 64 tile-blocks per dim
#define NTRI (NBLK * (NBLK + 1) / 2)  // 2080 upper-tri blocks

typedef __attribute__((ext_vector_type(8))) short bf16x8;   // 8 bf16 = 4 VGPRs
typedef __attribute__((ext_vector_type(4))) float f32x4;

typedef const __attribute__((address_space(1))) void* gas_ptr;
typedef __attribute__((address_space(3))) void* las_ptr;

// zn_perm layout: row r = g*16 + rr, k = c*32 + q*8 + j (j in [0,8)).
// element index P = (g*8 + c)*512 + q*128 + rr*8 + j
// => fragment (group g, chunk c) = contiguous 1 KB at byte (g*8+c)*1024, read
//    as lane*16 (lane = q*16 + rr). Matches mfma_16x16x32_bf16 A/B operand
//    layout (verified R3/R4/R5). 128-row slab = 64 KB contiguous.

// ---------------------------------------------------------------------------
// Kernel 1: wave-per-row normalize, permuted bf16 store; zero rowsum+ticket.
// No LDS, no barriers. 2048 blocks x 256 threads (4 rows/block).
// ---------------------------------------------------------------------------
__global__ __launch_bounds__(256) void normalize_kernel(
    const float* __restrict__ zi, const float* __restrict__ zj,
    __hip_bfloat16* __restrict__ zn, float* __restrict__ rowsum,
    unsigned int* __restrict__ ticket) {
  const int tid  = threadIdx.x;
  const int wave = tid >> 6;
  const int lane = tid & 63;
  const int r = blockIdx.x * 4 + wave;          // 0..8191
  const float* src = (r < PN) ? (zi + (size_t)r * PD) : (zj + (size_t)(r - PN) * PD);
  f32x4 x = *(const f32x4*)(src + lane * 4);    // k = lane*4 .. lane*4+3
  float s = x.x * x.x + x.y * x.y + x.z * x.z + x.w * x.w;
  #pragma unroll
  for (int off = 32; off >= 1; off >>= 1) s += __shfl_xor(s, off, 64);
  float inv = 1.0f / fmaxf(sqrtf(s), 1e-8f);
  // permuted dest: c=lane>>3, q=(lane>>1)&3, j=(lane&1)*4+jj (jj contiguous)
  int g = r >> 4, rr = r & 15;
  __hip_bfloat16* dst = zn + (size_t)(g * 8 + (lane >> 3)) * 512
                          + ((lane >> 1) & 3) * 128 + rr * 8 + (lane & 1) * 4;
  __hip_bfloat16 tmp[4];
  tmp[0] = __float2bfloat16(x.x * inv);
  tmp[1] = __float2bfloat16(x.y * inv);
  tmp[2] = __float2bfloat16(x.z * inv);
  tmp[3] = __float2bfloat16(x.w * inv);
  *(ushort4*)dst = *(ushort4*)tmp;              // 8 B aligned store
  if (blockIdx.x < 32) rowsum[blockIdx.x * 256 + tid] = 0.0f;  // ws poisoned 0xAA
  if (blockIdx.x == 0 && tid == 0) *ticket = 0;
}

// ---------------------------------------------------------------------------
// Kernel 2: sim = zn @ zn^T, upper-tri blocks. A-slab (64 KB) -> LDS via DMA,
// ONE barrier. B fragments prefetched to VGPRs: chunks 0-3 before the barrier
// (overlap the DMA), chunk c+4 issued before chunk c's MFMAs (~310 cyc cover).
// Last block (device ticket) runs the finalize reduction in-kernel.
// ---------------------------------------------------------------------------
__global__ __launch_bounds__(256, 2) void simsum_kernel(
    const __hip_bfloat16* __restrict__ zn, float* __restrict__ rowsum,
    float* __restrict__ pos, const float* __restrict__ w,
    unsigned int* __restrict__ ticket, float* __restrict__ out) {
  __shared__ char As[64 * 1024];   // A slab in zn_perm order: 8 groups x 8 KB
  __shared__ unsigned int tkt;
  __shared__ float pl[4], pw[4];

  // Decode upper-tri (bi<=bj) from linear index: T(bj)=bj(bj+1)/2
  const int idx = blockIdx.x;
  int bj = (int)((sqrtf(8.0f * (float)idx + 1.0f) - 1.0f) * 0.5f);
  while ((bj + 1) * (bj + 2) / 2 <= idx) ++bj;
  while (bj * (bj + 1) / 2 > idx) --bj;
  const int bi = idx - bj * (bj + 1) / 2;
  const bool diagBlk = (bi == bj);
  const bool posBlk  = (bj == bi + PN / TILE);   // cols == rows + 4096

  const int tid  = threadIdx.x;
  const int wave = tid >> 6;
  const int lane = tid & 63;
  const int quad = lane >> 4;
  const int c16  = lane & 15;
  const int wrow = bi * TILE + (wave >> 1) * 64;   // wave's 64-row slab
  const int wcol = bj * TILE + (wave & 1) * 64;    // wave's 64-col slab

  // Stage A slab: 64 KB contiguous, 16 wave-issues of 1 KB each.
  const char* aslab = (const char*)zn + (size_t)bi * 65536;
  #pragma unroll
  for (int p = 0; p < 16; ++p) {
    int off = (p * 4 + wave) * 1024;   // wave-uniform LDS base
    __builtin_amdgcn_global_load_lds((gas_ptr)(aslab + off + lane * 16),
                                     (las_ptr)(As + off), 16, 0, 0);
  }

  // B fragment base pointers (global): group = bj*8 + (wave&1)*4 + ni
  const __hip_bfloat16* bB[4];
  #pragma unroll
  for (int i = 0; i < 4; ++i)
    bB[i] = zn + (size_t)(bj * 8 + (wave & 1) * 4 + i) * 4096 + lane * 8;

  // Prefetch B chunks 0..3 — in flight alongside the A DMA.
  bf16x8 b[8][4];
  #pragma unroll
  for (int c = 0; c < 4; ++c)
    #pragma unroll
    for (int ni = 0; ni < 4; ++ni)
      b[c][ni] = *(const bf16x8*)(bB[ni] + c * 512);

  f32x4 acc[4][4];
  #pragma unroll
  for (int i = 0; i < 4; ++i)
    #pragma unroll
    for (int j = 0; j < 4; ++j)
      acc[i][j] = (f32x4){0.f, 0.f, 0.f, 0.f};

  const int arowg = (wave >> 1) * 4;   // wave's first A group in the slab

  __syncthreads();   // the ONLY barrier: A slab (and B chunks 0-3) resident

  #pragma unroll
  for (int c = 0; c < 8; ++c) {        // 8 chunks of K=32
    if (c < 4) {                       // software pipeline: prefetch c+4
      #pragma unroll
      for (int ni = 0; ni < 4; ++ni)
        b[c + 4][ni] = *(const bf16x8*)(bB[ni] + (c + 4) * 512);
    }
    bf16x8 a[4];
    #pragma unroll
    for (int mi = 0; mi < 4; ++mi)
      a[mi] = *(const bf16x8*)(As + ((arowg + mi) * 8 + c) * 1024 + lane * 16);
    #pragma unroll
    for (int mi = 0; mi < 4; ++mi)
      #pragma unroll
      for (int ni = 0; ni < 4; ++ni)
        acc[mi][ni] = __builtin_amdgcn_mfma_f32_16x16x32_bf16(a[mi], b[c][ni], acc[mi][ni], 0, 0, 0);
  }

  // Epilogue. C/D layout: col=lane&15, row=quad*4+reg  [measured m89/m91]
  float colsum[4] = {0.f, 0.f, 0.f, 0.f};
  #pragma unroll
  for (int mi = 0; mi < 4; ++mi) {
    int rbase = wrow + mi * 16 + quad * 4;
    float rs[4] = {0.f, 0.f, 0.f, 0.f};
    #pragma unroll
    for (int ni = 0; ni < 4; ++ni) {
      int gcol = wcol + ni * 16 + c16;
      #pragma unroll
      for (int t = 0; t < 4; ++t) {
        int grow = rbase + t;
        float sim = acc[mi][ni][t];
        float e = __expf(2.0f * sim);               // exp(sim / T), T=0.5
        if (diagBlk && gcol == grow) e = 0.0f;      // mask diagonal
        rs[t] += e;
        colsum[ni] += e;
        if (posBlk && gcol == grow + PN) {          // positive pair (and mirror)
          atomicExch(&pos[grow], sim);              // device-scope: cross-XCD safe
          atomicExch(&pos[grow + PN], sim);
        }
      }
    }
    #pragma unroll
    for (int t = 0; t < 4; ++t) {
      #pragma unroll
      for (int off = 1; off <= 8; off <<= 1) rs[t] += __shfl_xor(rs[t], off, 64);
    }
    if (c16 == 0) {
      #pragma unroll
      for (int t = 0; t < 4; ++t) atomicAdd(&rowsum[rbase + t], rs[t]);
    }
  }
  if (!diagBlk) {   // column contributions = mirrored rows (symmetry)
    #pragma unroll
    for (int ni = 0; ni < 4; ++ni) {
      float cs = colsum[ni];
      cs += __shfl_xor(cs, 16, 64);
      cs += __shfl_xor(cs, 32, 64);
      if (quad == 0) atomicAdd(&rowsum[wcol + ni * 16 + c16], cs);
    }
  }

  // ---- last-block finalize: loss_i = log(denom_i) - 2*pos_i; weighted mean
  __threadfence();                 // release our atomics before ticketing
  __syncthreads();
  if (tid == 0) tkt = atomicAdd(ticket, 1);
  __syncthreads();
  if (tkt == NTRI - 1) {           // all other blocks' writes are visible
    float wl = 0.f, wsum = 0.f;
    for (int i = tid; i < PN2; i += 256) {
      float rsv = __hip_atomic_load(&rowsum[i], __ATOMIC_RELAXED, __HIP_MEMORY_SCOPE_AGENT);
      float pv  = __hip_atomic_load(&pos[i],    __ATOMIC_RELAXED, __HIP_MEMORY_SCOPE_AGENT);
      float li = logf(rsv) - 2.0f * pv;
      float wi = w[i & (PN - 1)];
      wl += wi * li;
      wsum += wi;
    }
    #pragma unroll
    for (int off = 32; off >= 1; off >>= 1) {
      wl += __shfl_xor(wl, off, 64);
      wsum += __shfl_xor(wsum, off, 64);
    }
    if ((tid & 63) == 0) { pl[tid >> 6] = wl; pw[tid >> 6] = wsum; }
    __syncthreads();
    if (tid == 0)
      out[0] = (pl[0] + pl[1] + pl[2] + pl[3]) / (pw[0] + pw[1] + pw[2] + pw[3]);
  }
}

// ---------------------------------------------------------------------------
extern "C" void kernel_launch(void* const* d_in, const int* in_sizes, int n_in,
                              void* d_out, int out_size, void* d_ws, size_t ws_size,
                              hipStream_t stream) {
  const float* zi = (const float*)d_in[0];
  const float* zj = (const float*)d_in[1];
  const float* w  = (const float*)d_in[2];
  float* out = (float*)d_out;

  // Workspace: zn_perm bf16 [8192*256] = 4 MiB, rowsum f32[8192], pos f32[8192], ticket
  __hip_bfloat16* zn = (__hip_bfloat16*)d_ws;
  float* rowsum = (float*)((char*)d_ws + (size_t)PN2 * PD * 2);
  float* pos = rowsum + PN2;
  unsigned int* ticket = (unsigned int*)(pos + PN2);

  normalize_kernel<<<PN2 / 4, 256, 0, stream>>>(zi, zj, zn, rowsum, ticket);
  simsum_kernel<<<NTRI, 256, 0, stream>>>(zn, rowsum, pos, w, ticket, out);
}

// Round 7
// 218.815 us; speedup vs baseline: 1.0043x; 1.0043x over previous
//
#include <hip/hip_runtime.h>
#include <hip/hip_bf16.h>

// Problem constants (fixed by reference): N=4096, D=256, T=0.5, EPS=1e-8
#define PN   4096
#define PN2  8192
#define PD   256
#define TILE 128
#define NBLK (PN2 / TILE)             // 64 tile-blocks per dim
#define NTRI (NBLK * (NBLK + 1) / 2)  // 2080 upper-tri blocks

typedef __attribute__((ext_vector_type(8))) short bf16x8;   // 8 bf16 = 4 VGPRs
typedef __attribute__((ext_vector_type(4))) float f32x4;

typedef const __attribute__((address_space(1))) void* gas_ptr;
typedef __attribute__((address_space(3))) void* las_ptr;

// zn_perm layout: row r = g*16 + rr, k = c*32 + q*8 + j (j in [0,8)).
// element index P = (g*8 + c)*512 + q*128 + rr*8 + j
// => fragment (group g, chunk c) = contiguous 1 KB at byte (g*8+c)*1024, read
//    as lane*16 (lane = q*16 + rr). Matches mfma_16x16x32_bf16 A/B operand
//    layout (verified R3-R6). 128-row slab = 64 KB contiguous.

// ---------------------------------------------------------------------------
// Kernel 1: wave-per-row normalize, permuted bf16 store; zero rowsum+ticket.
// ---------------------------------------------------------------------------
__global__ __launch_bounds__(256) void normalize_kernel(
    const float* __restrict__ zi, const float* __restrict__ zj,
    __hip_bfloat16* __restrict__ zn, float* __restrict__ rowsum,
    unsigned int* __restrict__ ticket) {
  const int tid  = threadIdx.x;
  const int wave = tid >> 6;
  const int lane = tid & 63;
  const int r = blockIdx.x * 4 + wave;          // 0..8191
  const float* src = (r < PN) ? (zi + (size_t)r * PD) : (zj + (size_t)(r - PN) * PD);
  f32x4 x = *(const f32x4*)(src + lane * 4);    // k = lane*4 .. lane*4+3
  float s = x.x * x.x + x.y * x.y + x.z * x.z + x.w * x.w;
  #pragma unroll
  for (int off = 32; off >= 1; off >>= 1) s += __shfl_xor(s, off, 64);
  float inv = 1.0f / fmaxf(sqrtf(s), 1e-8f);
  int g = r >> 4, rr = r & 15;
  __hip_bfloat16* dst = zn + (size_t)(g * 8 + (lane >> 3)) * 512
                          + ((lane >> 1) & 3) * 128 + rr * 8 + (lane & 1) * 4;
  __hip_bfloat16 tmp[4];
  tmp[0] = __float2bfloat16(x.x * inv);
  tmp[1] = __float2bfloat16(x.y * inv);
  tmp[2] = __float2bfloat16(x.z * inv);
  tmp[3] = __float2bfloat16(x.w * inv);
  *(ushort4*)dst = *(ushort4*)tmp;              // 8 B aligned store
  if (blockIdx.x < 32) rowsum[blockIdx.x * 256 + tid] = 0.0f;  // ws poisoned 0xAA
  if (blockIdx.x == 0 && tid == 0) *ticket = 0;
}

// ---------------------------------------------------------------------------
// Kernel 2: sim = zn @ zn^T, upper-tri blocks. A-slab (64 KB) -> LDS via DMA,
// ONE barrier. B pipeline: 3 NAMED 4-fragment buffers (48 VGPRs, macro-expanded
// so all indices are constants -> no scratch). Chunks 0-2 prefetched before
// the barrier; chunk c+3 issued right after chunk c is consumed.
// Last block (device ticket) runs the finalize reduction in-kernel.
// ---------------------------------------------------------------------------
#define LOADB(BUF, c)                                                        \
  {                                                                          \
    _Pragma("unroll")                                                        \
    for (int ni = 0; ni < 4; ++ni)                                           \
      BUF[ni] = *(const bf16x8*)(bB[ni] + (c) * 512);                        \
  }

#define STEP(BUF, c)                                                         \
  {                                                                          \
    bf16x8 a[4];                                                             \
    _Pragma("unroll")                                                        \
    for (int mi = 0; mi < 4; ++mi)                                           \
      a[mi] = *(const bf16x8*)(As + ((arowg + mi) * 8 + (c)) * 1024 + lane * 16); \
    _Pragma("unroll")                                                        \
    for (int mi = 0; mi < 4; ++mi)                                           \
      _Pragma("unroll")                                                      \
      for (int ni = 0; ni < 4; ++ni)                                         \
        acc[mi][ni] = __builtin_amdgcn_mfma_f32_16x16x32_bf16(a[mi], BUF[ni], acc[mi][ni], 0, 0, 0); \
  }

__global__ __launch_bounds__(256, 2) void simsum_kernel(
    const __hip_bfloat16* __restrict__ zn, float* __restrict__ rowsum,
    float* __restrict__ pos, const float* __restrict__ w,
    unsigned int* __restrict__ ticket, float* __restrict__ out) {
  __shared__ char As[64 * 1024];   // A slab in zn_perm order: 8 groups x 8 KB
  __shared__ unsigned int tkt;
  __shared__ float pl[4], pw[4];

  // Decode upper-tri (bi<=bj) from linear index: T(bj)=bj(bj+1)/2
  const int idx = blockIdx.x;
  int bj = (int)((sqrtf(8.0f * (float)idx + 1.0f) - 1.0f) * 0.5f);
  while ((bj + 1) * (bj + 2) / 2 <= idx) ++bj;
  while (bj * (bj + 1) / 2 > idx) --bj;
  const int bi = idx - bj * (bj + 1) / 2;
  const bool diagBlk = (bi == bj);
  const bool posBlk  = (bj == bi + PN / TILE);   // cols == rows + 4096

  const int tid  = threadIdx.x;
  const int wave = tid >> 6;
  const int lane = tid & 63;
  const int quad = lane >> 4;
  const int c16  = lane & 15;
  const int wrow = bi * TILE + (wave >> 1) * 64;   // wave's 64-row slab
  const int wcol = bj * TILE + (wave & 1) * 64;    // wave's 64-col slab

  // Stage A slab: 64 KB contiguous, 16 wave-issues of 1 KB each.
  const char* aslab = (const char*)zn + (size_t)bi * 65536;
  #pragma unroll
  for (int p = 0; p < 16; ++p) {
    int off = (p * 4 + wave) * 1024;   // wave-uniform LDS base
    __builtin_amdgcn_global_load_lds((gas_ptr)(aslab + off + lane * 16),
                                     (las_ptr)(As + off), 16, 0, 0);
  }

  // B fragment base pointers (global): group = bj*8 + (wave&1)*4 + ni
  const __hip_bfloat16* bB[4];
  #pragma unroll
  for (int i = 0; i < 4; ++i)
    bB[i] = zn + (size_t)(bj * 8 + (wave & 1) * 4 + i) * 4096 + lane * 8;

  f32x4 acc[4][4];
  #pragma unroll
  for (int i = 0; i < 4; ++i)
    #pragma unroll
    for (int j = 0; j < 4; ++j)
      acc[i][j] = (f32x4){0.f, 0.f, 0.f, 0.f};

  const int arowg = (wave >> 1) * 4;   // wave's first A group in the slab

  // Prefetch B chunks 0-2 (in flight alongside the A DMA).
  bf16x8 b0[4], b1[4], b2[4];
  LOADB(b0, 0) LOADB(b1, 1) LOADB(b2, 2)

  __syncthreads();   // the ONLY barrier: A slab resident (drains vmcnt)

  STEP(b0, 0) LOADB(b0, 3)
  STEP(b1, 1) LOADB(b1, 4)
  STEP(b2, 2) LOADB(b2, 5)
  STEP(b0, 3) LOADB(b0, 6)
  STEP(b1, 4) LOADB(b1, 7)
  STEP(b2, 5)
  STEP(b0, 6)
  STEP(b1, 7)

  // Epilogue. C/D layout: col=lane&15, row=quad*4+reg  [measured m89/m91]
  float colsum[4] = {0.f, 0.f, 0.f, 0.f};
  #pragma unroll
  for (int mi = 0; mi < 4; ++mi) {
    int rbase = wrow + mi * 16 + quad * 4;
    float rs[4] = {0.f, 0.f, 0.f, 0.f};
    #pragma unroll
    for (int ni = 0; ni < 4; ++ni) {
      int gcol = wcol + ni * 16 + c16;
      #pragma unroll
      for (int t = 0; t < 4; ++t) {
        int grow = rbase + t;
        float sim = acc[mi][ni][t];
        float e = __expf(2.0f * sim);               // exp(sim / T), T=0.5
        if (diagBlk && gcol == grow) e = 0.0f;      // mask diagonal
        rs[t] += e;
        colsum[ni] += e;
        if (posBlk && gcol == grow + PN) {          // positive pair (and mirror)
          atomicExch(&pos[grow], sim);              // device-scope: cross-XCD safe
          atomicExch(&pos[grow + PN], sim);
        }
      }
    }
    #pragma unroll
    for (int t = 0; t < 4; ++t) {
      #pragma unroll
      for (int off = 1; off <= 8; off <<= 1) rs[t] += __shfl_xor(rs[t], off, 64);
    }
    if (c16 == 0) {
      #pragma unroll
      for (int t = 0; t < 4; ++t) atomicAdd(&rowsum[rbase + t], rs[t]);
    }
  }
  if (!diagBlk) {   // column contributions = mirrored rows (symmetry)
    #pragma unroll
    for (int ni = 0; ni < 4; ++ni) {
      float cs = colsum[ni];
      cs += __shfl_xor(cs, 16, 64);
      cs += __shfl_xor(cs, 32, 64);
      if (quad == 0) atomicAdd(&rowsum[wcol + ni * 16 + c16], cs);
    }
  }

  // ---- last-block finalize: loss_i = log(denom_i) - 2*pos_i; weighted mean
  __threadfence();                 // release our atomics before ticketing
  __syncthreads();
  if (tid == 0) tkt = atomicAdd(ticket, 1);
  __syncthreads();
  if (tkt == NTRI - 1) {           // all other blocks' writes are visible
    float wl = 0.f, wsum = 0.f;
    for (int i = tid; i < PN2; i += 256) {
      float rsv = __hip_atomic_load(&rowsum[i], __ATOMIC_RELAXED, __HIP_MEMORY_SCOPE_AGENT);
      float pv  = __hip_atomic_load(&pos[i],    __ATOMIC_RELAXED, __HIP_MEMORY_SCOPE_AGENT);
      float li = logf(rsv) - 2.0f * pv;
      float wi = w[i & (PN - 1)];
      wl += wi * li;
      wsum += wi;
    }
    #pragma unroll
    for (int off = 32; off >= 1; off >>= 1) {
      wl += __shfl_xor(wl, off, 64);
      wsum += __shfl_xor(wsum, off, 64);
    }
    if ((tid & 63) == 0) { pl[tid >> 6] = wl; pw[tid >> 6] = wsum; }
    __syncthreads();
    if (tid == 0)
      out[0] = (pl[0] + pl[1] + pl[2] + pl[3]) / (pw[0] + pw[1] + pw[2] + pw[3]);
  }
}

// ---------------------------------------------------------------------------
extern "C" void kernel_launch(void* const* d_in, const int* in_sizes, int n_in,
                              void* d_out, int out_size, void* d_ws, size_t ws_size,
                              hipStream_t stream) {
  const float* zi = (const float*)d_in[0];
  const float* zj = (const float*)d_in[1];
  const float* w  = (const float*)d_in[2];
  float* out = (float*)d_out;

  // Workspace: zn_perm bf16 [8192*256] = 4 MiB, rowsum f32[8192], pos f32[8192], ticket
  __hip_bfloat16* zn = (__hip_bfloat16*)d_ws;
  float* rowsum = (float*)((char*)d_ws + (size_t)PN2 * PD * 2);
  float* pos = rowsum + PN2;
  unsigned int* ticket = (unsigned int*)(pos + PN2);

  normalize_kernel<<<PN2 / 4, 256, 0, stream>>>(zi, zj, zn, rowsum, ticket);
  simsum_kernel<<<NTRI, 256, 0, stream>>>(zn, rowsum, pos, w, ticket, out);
}